// Round 3
// baseline (5352.094 us; speedup 1.0000x reference)
//
#include <hip/hip_runtime.h>
#include <stdint.h>

#define N_SITES 131072
#define CIN0 256
#define HID 512
#define KTAPS 9
#define NLAYERS 8

typedef __bf16 bf16x8 __attribute__((ext_vector_type(8)));
typedef float f32x4 __attribute__((ext_vector_type(4)));

__device__ __forceinline__ unsigned short f2bf(float f) {
    union { float f; unsigned u; } v; v.f = f;
    return (unsigned short)((v.u + 0x7fffu + ((v.u >> 16) & 1u)) >> 16);
}

// ---------------- prep kernels ----------------

__global__ void cvt_features_kernel(const float* __restrict__ in, unsigned short* __restrict__ out) {
    int t = blockIdx.x * 256 + threadIdx.x;
    const float4* p = (const float4*)in + 2 * (size_t)t;
    float4 a = p[0], b = p[1];
    uint4 o;
    o.x = f2bf(a.x) | ((unsigned)f2bf(a.y) << 16);
    o.y = f2bf(a.z) | ((unsigned)f2bf(a.w) << 16);
    o.z = f2bf(b.x) | ((unsigned)f2bf(b.y) << 16);
    o.w = f2bf(b.z) | ((unsigned)f2bf(b.w) << 16);
    ((uint4*)out)[t] = o;
}

__global__ void zero_rows_kernel(unsigned short* __restrict__ xf, unsigned short* __restrict__ xo) {
    int t = threadIdx.x; // 256 threads
    xf[(size_t)N_SITES * 512 + t] = 0;
    xf[(size_t)N_SITES * 512 + 256 + t] = 0;
    xo[(size_t)N_SITES * 256 + t] = 0;
    xo[(size_t)N_SITES * 512 + t] = 0;
    xo[(size_t)N_SITES * 512 + 256 + t] = 0;
}

// w fp32 [T][cin][512] -> bf16 [T][512][cin]
__global__ void transpose_w_kernel(const float* __restrict__ in, unsigned short* __restrict__ out, int cin) {
    __shared__ float tile[32][33];
    int m = blockIdx.z;
    int nb = blockIdx.x * 32;
    int cb = blockIdx.y * 32;
    int tx = threadIdx.x, ty = threadIdx.y;
    const float* src = in + (size_t)m * cin * HID;
    unsigned short* dst = out + (size_t)m * HID * cin;
#pragma unroll
    for (int j = 0; j < 4; ++j) {
        int r = ty + 8 * j;
        tile[r][tx] = src[(size_t)(cb + r) * HID + nb + tx];
    }
    __syncthreads();
#pragma unroll
    for (int j = 0; j < 4; ++j) {
        int r = ty + 8 * j;
        dst[(size_t)(nb + r) * cin + cb + tx] = f2bf(tile[tx][r]);
    }
}

// ---------------- 8-phase gathered GEMM + fused GroupNorm/ReLU ----------------

__device__ __forceinline__ void async16(const void* g, void* l) {
    __builtin_amdgcn_global_load_lds(
        (__attribute__((address_space(1))) unsigned int*)(g),
        (__attribute__((address_space(3))) unsigned int*)(l),
        16, 0, 0);
}

#define BARRIER() do { asm volatile("" ::: "memory"); __builtin_amdgcn_s_barrier(); asm volatile("" ::: "memory"); } while (0)
#define WAIT_LGKM0() asm volatile("s_waitcnt lgkmcnt(0)" ::: "memory")
#define WAIT_VM4() asm volatile("s_waitcnt vmcnt(4)" ::: "memory")
#define WAIT_VM0() asm volatile("s_waitcnt vmcnt(0)" ::: "memory")

#define MFMA4(I, A, B0_, B1_, B2_, B3_) \
    acc[I][0] = __builtin_amdgcn_mfma_f32_16x16x32_bf16(A, B0_, acc[I][0], 0, 0, 0); \
    acc[I][1] = __builtin_amdgcn_mfma_f32_16x16x32_bf16(A, B1_, acc[I][1], 0, 0, 0); \
    acc[I][2] = __builtin_amdgcn_mfma_f32_16x16x32_bf16(A, B2_, acc[I][2], 0, 0, 0); \
    acc[I][3] = __builtin_amdgcn_mfma_f32_16x16x32_bf16(A, B3_, acc[I][3], 0, 0, 0);

// 256x256 tile, BK=64, 8 waves (2M x 4N), double-buffered 128 KB LDS.
// K-halves (32 elems) are the staging unit; counted vmcnt(4) twice per K-step.
template<int CIN>
__global__ __launch_bounds__(512, 2) void subm_gemm_gn_8ph(
    const unsigned short* __restrict__ x,
    const int* __restrict__ nbr,
    const unsigned short* __restrict__ wt,
    const float* __restrict__ gamma,
    const float* __restrict__ beta,
    void* __restrict__ obuf,
    int write_bf16)
{
    constexpr int KK = CIN / 64;
    // buffer b (b=0,1): A at [b*4096 + kh*1024 + slot], B at [b*4096 + 2048 + kh*1024 + slot]
    // slot(row, cl) = (row>>1)*8 + (row&1)*4 + (cl ^ ((row>>1)&3))   (bank-optimal, 8-deep b128 reads)
    __shared__ uint4 lds[8192];           // 128 KB
    __shared__ int nbrS[256 * KTAPS];     // 9 KB: clamped neighbor ids (keeps K-loop VMEM = stage loads only)

    const int tid = threadIdx.x;
    const int lane = tid & 63;
    const int wave = tid >> 6;
    const int wm = (wave >> 2) * 128;     // 2 M-waves
    const int wn = (wave & 3) * 64;       // 4 N-waves

    // XCD swizzle: fixed col-tile per XCD, contiguous row sweep
    const int b = (int)blockIdx.x;
    const int xcd = b & 7;
    const int slot = b >> 3;              // 0..127
    const int colbase = (xcd & 1) * 256;
    const int rowbase = ((xcd >> 1) * 128 + slot) * 256;

    // staging geometry: thread covers rows {srow, srow+128}, logical chunk scl (16B within k-half)
    const int srow = 2 * (tid >> 3) + ((tid >> 2) & 1);
    const int scl = (tid & 3) ^ ((tid >> 3) & 3);
    const int ldsw = tid & ~63;           // wave-uniform slot base

    // preload clamped neighbor table
    for (int u = tid; u < 256 * KTAPS; u += 512) {
        int v = nbr[(size_t)rowbase * KTAPS + u];
        nbrS[u] = (v < 0) ? N_SITES : v;
    }
    __syncthreads();

    const f32x4 zero4 = {0.f, 0.f, 0.f, 0.f};
    f32x4 acc[8][4];
#pragma unroll
    for (int i = 0; i < 8; ++i)
#pragma unroll
        for (int j = 0; j < 4; ++j)
            acc[i][j] = zero4;

    auto stageA = [&](int i0, int i1, int kkp, int kh, int buf) {
        const unsigned short* g0 = x + (size_t)i0 * CIN + kkp * 64 + kh * 32 + scl * 8;
        const unsigned short* g1 = x + (size_t)i1 * CIN + kkp * 64 + kh * 32 + scl * 8;
        async16(g0, &lds[buf * 4096 + kh * 1024 + ldsw]);
        async16(g1, &lds[buf * 4096 + kh * 1024 + 512 + ldsw]);
    };
    auto stageB = [&](int tp, int kkp, int kh, int buf) {
        const unsigned short* g0 = wt + (size_t)(tp * HID + colbase + srow) * CIN + kkp * 64 + kh * 32 + scl * 8;
        const unsigned short* g1 = wt + (size_t)(tp * HID + colbase + srow + 128) * CIN + kkp * 64 + kh * 32 + scl * 8;
        async16(g0, &lds[buf * 4096 + 2048 + kh * 1024 + ldsw]);
        async16(g1, &lds[buf * 4096 + 2048 + kh * 1024 + 512 + ldsw]);
    };
    auto rdA = [&](int i, int ks, int buf) {
        int rl = wm + i * 16 + (lane & 15);
        return __builtin_bit_cast(bf16x8,
            lds[buf * 4096 + ks * 1024 + (rl >> 1) * 8 + (rl & 1) * 4 + ((lane >> 4) ^ ((rl >> 1) & 3))]);
    };
    auto rdB = [&](int j, int ks, int buf) {
        int rn = wn + j * 16 + (lane & 15);
        return __builtin_bit_cast(bf16x8,
            lds[buf * 4096 + 2048 + ks * 1024 + (rn >> 1) * 8 + (rn & 1) * 4 + ((lane >> 4) ^ ((rn >> 1) & 3))]);
    };

    // prologue: stage K-step 0 (tap 0, kk 0) in order Ak0, Bk0, Ak1, Bk1
    {
        int a0 = nbrS[srow * KTAPS], a1 = nbrS[(srow + 128) * KTAPS];
        stageA(a0, a1, 0, 0, 0);
        stageB(0, 0, 0, 0);
        stageA(a0, a1, 0, 1, 0);
        stageB(0, 0, 1, 0);
    }
    WAIT_VM4();
    BARRIER();

    for (int tap = 0; tap < KTAPS; ++tap) {
#pragma unroll 2
        for (int kk = 0; kk < KK; ++kk) {
            const int p = kk & 1;          // compute buffer (tap*KK even)
            const int q = p ^ 1;           // stage target
            const bool haveNext = !(tap == KTAPS - 1 && kk == KK - 1);
            const int ntap = (kk == KK - 1) ? tap + 1 : tap;
            const int nkk = (kk == KK - 1) ? 0 : kk + 1;
            int nA0 = 0, nA1 = 0;
            if (haveNext) {
                nA0 = nbrS[srow * KTAPS + ntap];
                nA1 = nbrS[(srow + 128) * KTAPS + ntap];
            }
            // ---- phase 0: stage next Ak0; compute i0-3 x ks0 ----
            if (haveNext) stageA(nA0, nA1, nkk, 0, q);
            bf16x8 a0 = rdA(0, 0, p), a1 = rdA(1, 0, p), a2 = rdA(2, 0, p), a3 = rdA(3, 0, p);
            bf16x8 b0 = rdB(0, 0, p), b1 = rdB(1, 0, p), b2 = rdB(2, 0, p), b3 = rdB(3, 0, p);
            BARRIER();
            WAIT_LGKM0();
            __builtin_amdgcn_s_setprio(1);
            MFMA4(0, a0, b0, b1, b2, b3)
            MFMA4(1, a1, b0, b1, b2, b3)
            MFMA4(2, a2, b0, b1, b2, b3)
            MFMA4(3, a3, b0, b1, b2, b3)
            __builtin_amdgcn_s_setprio(0);
            BARRIER();
            // ---- phase 1: stage next Bk0; compute i4-7 x ks0 ----
            if (haveNext) stageB(ntap, nkk, 0, q);
            {
                bf16x8 a4 = rdA(4, 0, p), a5 = rdA(5, 0, p), a6 = rdA(6, 0, p), a7 = rdA(7, 0, p);
                BARRIER();
                WAIT_LGKM0();
                __builtin_amdgcn_s_setprio(1);
                MFMA4(4, a4, b0, b1, b2, b3)
                MFMA4(5, a5, b0, b1, b2, b3)
                MFMA4(6, a6, b0, b1, b2, b3)
                MFMA4(7, a7, b0, b1, b2, b3)
                __builtin_amdgcn_s_setprio(0);
            }
            if (haveNext) { WAIT_VM4(); } else { WAIT_VM0(); }   // publish this step's Ak1,Bk1
            BARRIER();
            // ---- phase 2: stage next Ak1; compute i0-3 x ks1 ----
            if (haveNext) stageA(nA0, nA1, nkk, 1, q);
            a0 = rdA(0, 1, p); a1 = rdA(1, 1, p); a2 = rdA(2, 1, p); a3 = rdA(3, 1, p);
            b0 = rdB(0, 1, p); b1 = rdB(1, 1, p); b2 = rdB(2, 1, p); b3 = rdB(3, 1, p);
            BARRIER();
            WAIT_LGKM0();
            __builtin_amdgcn_s_setprio(1);
            MFMA4(0, a0, b0, b1, b2, b3)
            MFMA4(1, a1, b0, b1, b2, b3)
            MFMA4(2, a2, b0, b1, b2, b3)
            MFMA4(3, a3, b0, b1, b2, b3)
            __builtin_amdgcn_s_setprio(0);
            BARRIER();
            // ---- phase 3: stage next Bk1; compute i4-7 x ks1 ----
            if (haveNext) stageB(ntap, nkk, 1, q);
            {
                bf16x8 a4 = rdA(4, 1, p), a5 = rdA(5, 1, p), a6 = rdA(6, 1, p), a7 = rdA(7, 1, p);
                BARRIER();
                WAIT_LGKM0();
                __builtin_amdgcn_s_setprio(1);
                MFMA4(4, a4, b0, b1, b2, b3)
                MFMA4(5, a5, b0, b1, b2, b3)
                MFMA4(6, a6, b0, b1, b2, b3)
                MFMA4(7, a7, b0, b1, b2, b3)
                __builtin_amdgcn_s_setprio(0);
            }
            WAIT_VM4();                     // publish next step's Ak0,Bk0 (no-op on last)
            BARRIER();
        }
    }

    // ---- fused GroupNorm + ReLU epilogue (LDS transpose, 2 passes of 128 rows) ----
    __syncthreads();
    float* E = (float*)lds;                 // [col 256][row 128] f32, XOR-swizzled rows
    const int seg = tid & 31;               // 8-col segment
    const int qv = tid >> 5;                // base row-quad
    const int c0s = seg * 8;
    unsigned short* bf_out = (unsigned short*)obuf;
    float* f_out = (float*)obuf;

    float gv[8], bv[8];
#pragma unroll
    for (int k = 0; k < 8; ++k) {
        gv[k] = gamma[colbase + c0s + k];
        bv[k] = beta[colbase + c0s + k];
    }

#pragma unroll
    for (int pass = 0; pass < 2; ++pass) {
        if (pass) __syncthreads();
        // stage fragments i in {4p..4p+3} -> E
#pragma unroll
        for (int ii = 0; ii < 4; ++ii) {
#pragma unroll
            for (int j = 0; j < 4; ++j) {
                const int col = wn + j * 16 + (lane & 15);
                const int lrow = (wm >> 1) + ii * 16 + (lane >> 4) * 4;
                *(f32x4*)&E[col * 128 + (lrow ^ (((col >> 3) & 7) << 2))] = acc[pass * 4 + ii][j];
            }
        }
        __syncthreads();
#pragma unroll
        for (int h = 0; h < 2; ++h) {
            const int r0w = (qv + h * 16) * 4;  // quad base row 0..124
            f32x4 vv[8];
            f32x4 s = zero4, q2 = zero4;
#pragma unroll
            for (int cc = 0; cc < 8; ++cc) {
                const int col = c0s + cc;
                vv[cc] = *(const f32x4*)&E[col * 128 + (r0w ^ (((col >> 3) & 7) << 2))];
                s += vv[cc];
                q2 += vv[cc] * vv[cc];
            }
            f32x4 mu, rs;
#pragma unroll
            for (int r = 0; r < 4; ++r) {
                s[r] += __shfl_xor(s[r], 1);
                q2[r] += __shfl_xor(q2[r], 1);
                mu[r] = s[r] * 0.0625f;
                rs[r] = rsqrtf(q2[r] * 0.0625f - mu[r] * mu[r] + 1e-5f);
            }
            if (write_bf16) {
#pragma unroll
                for (int r = 0; r < 4; ++r) {
                    const int l = r0w + r;
                    const int grow = rowbase + 64 * pass + (l & 63) + ((l >> 6) << 7);
                    unsigned pk[4];
#pragma unroll
                    for (int cp = 0; cp < 4; ++cp) {
                        float ya = fmaxf(0.f, (vv[2 * cp][r] - mu[r]) * rs[r] * gv[2 * cp] + bv[2 * cp]);
                        float yb = fmaxf(0.f, (vv[2 * cp + 1][r] - mu[r]) * rs[r] * gv[2 * cp + 1] + bv[2 * cp + 1]);
                        pk[cp] = f2bf(ya) | ((unsigned)f2bf(yb) << 16);
                    }
                    uint4 o; o.x = pk[0]; o.y = pk[1]; o.z = pk[2]; o.w = pk[3];
                    *(uint4*)&bf_out[(size_t)grow * HID + colbase + c0s] = o;
                }
            } else {
#pragma unroll
                for (int r = 0; r < 4; ++r) {
                    const int l = r0w + r;
                    const int grow = rowbase + 64 * pass + (l & 63) + ((l >> 6) << 7);
                    f32x4 ya, yb;
#pragma unroll
                    for (int k = 0; k < 4; ++k) {
                        ya[k] = fmaxf(0.f, (vv[k][r] - mu[r]) * rs[r] * gv[k] + bv[k]);
                        yb[k] = fmaxf(0.f, (vv[4 + k][r] - mu[r]) * rs[r] * gv[4 + k] + bv[4 + k]);
                    }
                    float* dst = f_out + (size_t)grow * HID + colbase + c0s;
                    *(f32x4*)dst = ya;
                    *(f32x4*)(dst + 4) = yb;
                }
            }
        }
    }
}

// ---------------- launch ----------------

extern "C" void kernel_launch(void* const* d_in, const int* in_sizes, int n_in,
                              void* d_out, int out_size, void* d_ws, size_t ws_size,
                              hipStream_t stream) {
    const float* features = (const float*)d_in[0];
    const int*   nbr      = (const int*)d_in[1];
    const float* w0       = (const float*)d_in[2];
    const float* w_rest   = (const float*)d_in[3];
    const float* gamma    = (const float*)d_in[4];
    const float* beta     = (const float*)d_in[5];

    // Ping-pong bf16 activation buffers: F = workspace, O = alias of d_out.
    // cvt->O, L0: O->F, L1: F->O, ..., L6: O->F, L7: F->d_out(f32).
    unsigned short* xF = (unsigned short*)d_ws;
    size_t xbytes = (size_t)(N_SITES + 1) * HID * sizeof(unsigned short);
    unsigned short* w0t = (unsigned short*)((char*)d_ws + xbytes);
    size_t w0t_bytes = (size_t)KTAPS * HID * CIN0 * sizeof(unsigned short);
    unsigned short* wrt = (unsigned short*)((char*)d_ws + xbytes + w0t_bytes);
    unsigned short* xO = (unsigned short*)d_out;

    cvt_features_kernel<<<N_SITES * CIN0 / (256 * 8), 256, 0, stream>>>(features, xO);
    zero_rows_kernel<<<1, 256, 0, stream>>>(xF, xO);
    transpose_w_kernel<<<dim3(HID / 32, CIN0 / 32, KTAPS), dim3(32, 8), 0, stream>>>(w0, w0t, CIN0);
    transpose_w_kernel<<<dim3(HID / 32, HID / 32, (NLAYERS - 1) * KTAPS), dim3(32, 8), 0, stream>>>(w_rest, wrt, HID);

    for (int l = 0; l < NLAYERS; ++l) {
        const unsigned short* wt = (l == 0) ? w0t : wrt + (size_t)(l - 1) * KTAPS * HID * HID;
        const unsigned short* xin = (l & 1) ? xF : xO;
        void* obuf = (l == NLAYERS - 1) ? d_out : (void*)((l & 1) ? xO : xF);
        const float* g = gamma + (size_t)l * HID;
        const float* bt = beta + (size_t)l * HID;
        int wb = (l < NLAYERS - 1) ? 1 : 0;
        if (l == 0)
            subm_gemm_gn_8ph<CIN0><<<(N_SITES / 256) * 2, 512, 0, stream>>>(xin, nbr, wt, g, bt, obuf, wb);
        else
            subm_gemm_gn_8ph<HID><<<(N_SITES / 256) * 2, 512, 0, stream>>>(xin, nbr, wt, g, bt, obuf, wb);
    }
}

// Round 4
// 4868.165 us; speedup vs baseline: 1.0994x; 1.0994x over previous
//
#include <hip/hip_runtime.h>
#include <stdint.h>

#define N_SITES 131072
#define CIN0 256
#define HID 512
#define KTAPS 9
#define NLAYERS 8

typedef __bf16 bf16x8 __attribute__((ext_vector_type(8)));
typedef float f32x4 __attribute__((ext_vector_type(4)));

__device__ __forceinline__ unsigned short f2bf(float f) {
    union { float f; unsigned u; } v; v.f = f;
    return (unsigned short)((v.u + 0x7fffu + ((v.u >> 16) & 1u)) >> 16);
}

// ---------------- prep kernels ----------------

__global__ void cvt_features_kernel(const float* __restrict__ in, unsigned short* __restrict__ out) {
    int t = blockIdx.x * 256 + threadIdx.x;
    const float4* p = (const float4*)in + 2 * (size_t)t;
    float4 a = p[0], b = p[1];
    uint4 o;
    o.x = f2bf(a.x) | ((unsigned)f2bf(a.y) << 16);
    o.y = f2bf(a.z) | ((unsigned)f2bf(a.w) << 16);
    o.z = f2bf(b.x) | ((unsigned)f2bf(b.y) << 16);
    o.w = f2bf(b.z) | ((unsigned)f2bf(b.w) << 16);
    ((uint4*)out)[t] = o;
}

__global__ void zero_rows_kernel(unsigned short* __restrict__ xf, unsigned short* __restrict__ xo) {
    int t = threadIdx.x; // 256 threads
    xf[(size_t)N_SITES * 512 + t] = 0;
    xf[(size_t)N_SITES * 512 + 256 + t] = 0;
    xo[(size_t)N_SITES * 256 + t] = 0;
    xo[(size_t)N_SITES * 512 + t] = 0;
    xo[(size_t)N_SITES * 512 + 256 + t] = 0;
}

// w fp32 [T][cin][512] -> bf16 [T][512][cin]
__global__ void transpose_w_kernel(const float* __restrict__ in, unsigned short* __restrict__ out, int cin) {
    __shared__ float tile[32][33];
    int m = blockIdx.z;
    int nb = blockIdx.x * 32;
    int cb = blockIdx.y * 32;
    int tx = threadIdx.x, ty = threadIdx.y;
    const float* src = in + (size_t)m * cin * HID;
    unsigned short* dst = out + (size_t)m * HID * cin;
#pragma unroll
    for (int j = 0; j < 4; ++j) {
        int r = ty + 8 * j;
        tile[r][tx] = src[(size_t)(cb + r) * HID + nb + tx];
    }
    __syncthreads();
#pragma unroll
    for (int j = 0; j < 4; ++j) {
        int r = ty + 8 * j;
        dst[(size_t)(nb + r) * cin + cb + tx] = f2bf(tile[tx][r]);
    }
}

// ---------------- gathered GEMM + fused GroupNorm/ReLU ----------------

__device__ __forceinline__ void async16(const void* g, void* l) {
    __builtin_amdgcn_global_load_lds(
        (__attribute__((address_space(1))) unsigned int*)(g),
        (__attribute__((address_space(3))) unsigned int*)(l),
        16, 0, 0);
}

#define BARRIER() do { asm volatile("" ::: "memory"); __builtin_amdgcn_s_barrier(); asm volatile("" ::: "memory"); } while (0)
#define WAIT_VM3() asm volatile("s_waitcnt vmcnt(3)" ::: "memory")
#define WAIT_VM0() asm volatile("s_waitcnt vmcnt(0)" ::: "memory")

// 128x256 tile, BK=32, 8 waves (2M x 4N -> 64x64/wave), triple-buffered ring,
// counted vmcnt(3), single barrier per K-step, 2 blocks/CU (4 waves/SIMD TLP).
template<int CIN>
__global__ __launch_bounds__(512, 4) void subm_gemm_gn_p2(
    const unsigned short* __restrict__ x,
    const int* __restrict__ nbr,
    const unsigned short* __restrict__ wt,
    const float* __restrict__ gamma,
    const float* __restrict__ beta,
    void* __restrict__ obuf,
    int write_bf16)
{
    constexpr int KK = CIN / 32;          // K-steps per tap
    // A ring: 3 x 512 uint4 (128 rows x 32k), B ring: 3 x 1024 uint4 (256 rows x 32k)
    // slot(r,c) = (r>>1)*8 + (r&1)*4 + (c ^ ((r>>1)&3))  -> 2-way (free) b128 reads
    __shared__ uint4 lds[4608];           // 72 KB (also reused as f32 epilogue buffer)
    __shared__ int nbrS[128 * KTAPS];     // 4.5 KB

    const int tid = threadIdx.x;
    const int lane = tid & 63;
    const int wave = tid >> 6;
    const int wm = (wave >> 2) * 64;      // 2 M-groups
    const int wn = (wave & 3) * 64;       // 4 N-groups

    // XCD swizzle: fixed col-tile per XCD (B slice L2-resident), contiguous row sweep
    const int b = (int)blockIdx.x;
    const int xcd = b & 7;
    const int slot = b >> 3;              // 0..255
    const int colbase = (xcd & 1) * 256;
    const int rowbase = ((xcd >> 1) * 256 + slot) * 128;

    // staging geometry (paired-row, pre-swizzled global chunk)
    const int srow = 2 * (tid >> 3) + ((tid >> 2) & 1);  // 0..127
    const int scl = (tid & 3) ^ ((tid >> 3) & 3);        // 16B chunk within 32-k row
    const int ldsw = tid & ~63;                          // wave-uniform dest base (uint4)

    for (int u = tid; u < 128 * KTAPS; u += 512) {
        int v = nbr[(size_t)rowbase * KTAPS + u];
        nbrS[u] = (v < 0) ? N_SITES : v;
    }
    __syncthreads();

    const f32x4 zero4 = {0.f, 0.f, 0.f, 0.f};
    f32x4 acc[4][4];
#pragma unroll
    for (int i = 0; i < 4; ++i)
#pragma unroll
        for (int j = 0; j < 4; ++j)
            acc[i][j] = zero4;

    auto stageA = [&](int trow, int kk2, int s) {
        async16(x + (size_t)trow * CIN + kk2 * 32 + scl * 8, &lds[s * 512 + ldsw]);
    };
    auto stageB = [&](int ttap, int kk2, int s) {
        const unsigned short* g = wt + ((size_t)ttap * HID + colbase + srow) * CIN + kk2 * 32 + scl * 8;
        async16(g, &lds[1536 + s * 1024 + ldsw]);
        async16(g + (size_t)128 * CIN, &lds[1536 + s * 1024 + 512 + ldsw]);
    };
    auto rdA = [&](int i, int s) {
        int rl = wm + i * 16 + (lane & 15);
        return __builtin_bit_cast(bf16x8,
            lds[s * 512 + (rl >> 1) * 8 + (rl & 1) * 4 + ((lane >> 4) ^ ((rl >> 1) & 3))]);
    };
    auto rdB = [&](int j, int s) {
        int rn = wn + j * 16 + (lane & 15);
        return __builtin_bit_cast(bf16x8,
            lds[1536 + s * 1024 + (rn >> 1) * 8 + (rn & 1) * 4 + ((lane >> 4) ^ ((rn >> 1) & 3))]);
    };

    // prologue: stage K-steps 0 and 1 (tap 0)
    int rcur = nbrS[srow * KTAPS + 0];
    stageA(rcur, 0, 0);
    stageB(0, 0, 0);
    stageA(rcur, 1, 1);
    stageB(0, 1, 1);
    WAIT_VM3();          // step-0 data published, step-1's 3 loads stay in flight
    BARRIER();

    int cur = 0;
    for (int tap = 0; tap < KTAPS; ++tap) {
        const int rnext = (tap + 1 < KTAPS) ? nbrS[srow * KTAPS + tap + 1] : 0;
        for (int kk = 0; kk < KK; ++kk) {
            const bool haveStage = !(tap == KTAPS - 1 && kk >= KK - 2);
            const int stg = (cur >= 1) ? cur - 1 : 2;     // (cur+2)%3
            if (haveStage) {
                int kk2 = kk + 2, ttap = tap, trow = rcur;
                if (kk2 >= KK) { kk2 -= KK; ttap = tap + 1; trow = rnext; }
                stageA(trow, kk2, stg);
                stageB(ttap, kk2, stg);
            }
            bf16x8 af[4], bfr[4];
#pragma unroll
            for (int f = 0; f < 4; ++f) { af[f] = rdA(f, cur); bfr[f] = rdB(f, cur); }
            __builtin_amdgcn_s_setprio(1);
#pragma unroll
            for (int i = 0; i < 4; ++i)
#pragma unroll
                for (int j = 0; j < 4; ++j)
                    acc[i][j] = __builtin_amdgcn_mfma_f32_16x16x32_bf16(af[i], bfr[j], acc[i][j], 0, 0, 0);
            __builtin_amdgcn_s_setprio(0);
            if (haveStage) { WAIT_VM3(); } else { WAIT_VM0(); }
            BARRIER();
            cur = (cur < 2) ? cur + 1 : 0;
        }
        rcur = rnext;
    }

    // ---- fused GroupNorm + ReLU epilogue (LDS transpose, 2 passes of 64 rows) ----
    __syncthreads();
    float* E = (float*)lds;               // [col 256][row 64] f32, XOR-swizzled rows
    const int seg = tid & 31;             // 8-col segment
    const int qv = tid >> 5;              // 0..15 row-quad
    const int c0s = seg * 8;
    unsigned short* bf_out = (unsigned short*)obuf;
    float* f_out = (float*)obuf;

    float gv[8], bv[8];
#pragma unroll
    for (int k = 0; k < 8; ++k) {
        gv[k] = gamma[colbase + c0s + k];
        bv[k] = beta[colbase + c0s + k];
    }
    const int growbase = rowbase + (qv >> 3) * 64 + ((qv >> 2) & 1) * 16 + (qv & 3) * 4;

#pragma unroll
    for (int pass = 0; pass < 2; ++pass) {
        if (pass) __syncthreads();
        // stage acc[2p+ii][j] from all waves -> E (64 rows x 256 cols)
#pragma unroll
        for (int ii = 0; ii < 2; ++ii) {
#pragma unroll
            for (int j = 0; j < 4; ++j) {
                const int col = wn + j * 16 + (lane & 15);
                const int lrow = (wm >> 1) + ii * 16 + (lane >> 4) * 4;
                *(f32x4*)&E[col * 64 + (lrow ^ (((col >> 3) & 7) << 2))] = acc[pass * 2 + ii][j];
            }
        }
        __syncthreads();

        const int r0w = qv * 4;
        f32x4 vv[8];
        f32x4 s = zero4, q2 = zero4;
#pragma unroll
        for (int cc = 0; cc < 8; ++cc) {
            const int col = c0s + cc;
            vv[cc] = *(const f32x4*)&E[col * 64 + (r0w ^ (((col >> 3) & 7) << 2))];
            s += vv[cc];
            q2 += vv[cc] * vv[cc];
        }
        f32x4 mu, rs;
#pragma unroll
        for (int r = 0; r < 4; ++r) {
            s[r] += __shfl_xor(s[r], 1);
            q2[r] += __shfl_xor(q2[r], 1);
            mu[r] = s[r] * 0.0625f;
            rs[r] = rsqrtf(q2[r] * 0.0625f - mu[r] * mu[r] + 1e-5f);
        }
        if (write_bf16) {
#pragma unroll
            for (int r = 0; r < 4; ++r) {
                const int grow = growbase + pass * 32 + r;
                unsigned pk[4];
#pragma unroll
                for (int cp = 0; cp < 4; ++cp) {
                    float ya = fmaxf(0.f, (vv[2 * cp][r] - mu[r]) * rs[r] * gv[2 * cp] + bv[2 * cp]);
                    float yb = fmaxf(0.f, (vv[2 * cp + 1][r] - mu[r]) * rs[r] * gv[2 * cp + 1] + bv[2 * cp + 1]);
                    pk[cp] = f2bf(ya) | ((unsigned)f2bf(yb) << 16);
                }
                uint4 o; o.x = pk[0]; o.y = pk[1]; o.z = pk[2]; o.w = pk[3];
                *(uint4*)&bf_out[(size_t)grow * HID + colbase + c0s] = o;
            }
        } else {
#pragma unroll
            for (int r = 0; r < 4; ++r) {
                const int grow = growbase + pass * 32 + r;
                f32x4 ya, yb;
#pragma unroll
                for (int k = 0; k < 4; ++k) {
                    ya[k] = fmaxf(0.f, (vv[k][r] - mu[r]) * rs[r] * gv[k] + bv[k]);
                    yb[k] = fmaxf(0.f, (vv[4 + k][r] - mu[r]) * rs[r] * gv[4 + k] + bv[4 + k]);
                }
                float* dst = f_out + (size_t)grow * HID + colbase + c0s;
                *(f32x4*)dst = ya;
                *(f32x4*)(dst + 4) = yb;
            }
        }
    }
}

// ---------------- launch ----------------

extern "C" void kernel_launch(void* const* d_in, const int* in_sizes, int n_in,
                              void* d_out, int out_size, void* d_ws, size_t ws_size,
                              hipStream_t stream) {
    const float* features = (const float*)d_in[0];
    const int*   nbr      = (const int*)d_in[1];
    const float* w0       = (const float*)d_in[2];
    const float* w_rest   = (const float*)d_in[3];
    const float* gamma    = (const float*)d_in[4];
    const float* beta     = (const float*)d_in[5];

    // Ping-pong bf16 activation buffers: F = workspace, O = alias of d_out.
    // cvt->O, L0: O->F, L1: F->O, ..., L6: O->F, L7: F->d_out(f32).
    unsigned short* xF = (unsigned short*)d_ws;
    size_t xbytes = (size_t)(N_SITES + 1) * HID * sizeof(unsigned short);
    unsigned short* w0t = (unsigned short*)((char*)d_ws + xbytes);
    size_t w0t_bytes = (size_t)KTAPS * HID * CIN0 * sizeof(unsigned short);
    unsigned short* wrt = (unsigned short*)((char*)d_ws + xbytes + w0t_bytes);
    unsigned short* xO = (unsigned short*)d_out;

    cvt_features_kernel<<<N_SITES * CIN0 / (256 * 8), 256, 0, stream>>>(features, xO);
    zero_rows_kernel<<<1, 256, 0, stream>>>(xF, xO);
    transpose_w_kernel<<<dim3(HID / 32, CIN0 / 32, KTAPS), dim3(32, 8), 0, stream>>>(w0, w0t, CIN0);
    transpose_w_kernel<<<dim3(HID / 32, HID / 32, (NLAYERS - 1) * KTAPS), dim3(32, 8), 0, stream>>>(w_rest, wrt, HID);

    for (int l = 0; l < NLAYERS; ++l) {
        const unsigned short* wt = (l == 0) ? w0t : wrt + (size_t)(l - 1) * KTAPS * HID * HID;
        const unsigned short* xin = (l & 1) ? xF : xO;
        void* obuf = (l == NLAYERS - 1) ? d_out : (void*)((l & 1) ? xO : xF);
        const float* g = gamma + (size_t)l * HID;
        const float* bt = beta + (size_t)l * HID;
        int wb = (l < NLAYERS - 1) ? 1 : 0;
        if (l == 0)
            subm_gemm_gn_p2<CIN0><<<(N_SITES / 128) * 2, 512, 0, stream>>>(xin, nbr, wt, g, bt, obuf, wb);
        else
            subm_gemm_gn_p2<HID><<<(N_SITES / 128) * 2, 512, 0, stream>>>(xin, nbr, wt, g, bt, obuf, wb);
    }
}